// Round 5
// baseline (2452.751 us; speedup 1.0000x reference)
//
#include <hip/hip_runtime.h>

// Correlation (FlowNet-style), kernel=1, stride=1, md=pad=4.
// B=8, C=128, H=W=192 -> out [8, 81, 192, 192] fp32.
//
// Round-5: no LDS, no barriers; 9-wave blocks + 3-buffer rotating pipeline.
//  - 1152 blocks (8b x 6xt x 24yt), tile 8y x 32x, 576 thr = 9 waves,
//    wave w = dy. All 9 dy consumers of an x2 row are co-resident in one
//    block -> x2 re-reads hit L1/L2. XCD k == batch k via swizzle.
//  - thread: 4 x px; per channel 1 x1 float4 + 3 x2 float4 -> 36 FMA.
//  - software pipeline: period-3 buffer rotation (A,B,C), prefetch
//    distance = 2 channel-bodies (~800 wall cycles), zero reg copies.
//  - __launch_bounds__(576,5): cap VGPR at 102 so 2 blocks (18 waves)/CU.

#define NT 576

__global__ __launch_bounds__(NT, 5)
void corr_kernel(const float* __restrict__ x1g, const float* __restrict__ x2g,
                 float* __restrict__ outg) {
  constexpr int Cc = 128, Hh = 192, Ww = 192, HW = Hh * Ww;

  // XCD-chunked swizzle: XCD k (bid%8) gets tiles k*144..k*144+143 = batch k.
  const int bid  = blockIdx.x;
  const int tile = (bid & 7) * 144 + (bid >> 3);
  const int yt = tile % 24;
  const int t2 = tile / 24;
  const int xt = t2 % 6;
  const int b  = t2 / 6;
  const int y0 = yt * 8, x0 = xt * 32;

  const int tid  = (int)threadIdx.x;
  const int dy   = tid >> 6;    // wave index = dy (0..8)
  const int lane = tid & 63;
  const int tx   = lane & 7;    // 4 px each -> 32 cols
  const int ty   = lane >> 3;   // 8 rows

  const int y  = y0 + ty;
  const int xb = x0 + 4 * tx;
  const int row = y + dy - 4;
  const bool rowok = (row >= 0) && (row < Hh);
  const int rowc = rowok ? row : 0;

  // x2 window cols xb-4..xb+7; float4 slots fully in- or out-of-range.
  const bool ok0 = rowok && (xb >= 4);
  const bool ok1 = rowok;
  const bool ok2 = rowok && (xb <= 184);

  const float* p1 = x1g + ((size_t)(b * Cc) * Hh + y) * Ww + xb;
  const float* p2 = x2g + ((size_t)(b * Cc) * Hh + rowc) * Ww + (xb - 4);

  float acc[9][4];
#pragma unroll
  for (int d = 0; d < 9; ++d)
#pragma unroll
    for (int q = 0; q < 4; ++q) acc[d][q] = 0.f;

  const float4 z4 = make_float4(0.f, 0.f, 0.f, 0.f);
  float4 aA, c0A, c1A, c2A;
  float4 aB, c0B, c1B, c2B;
  float4 aC, c0C, c1C, c2C;

#define LOADSET(Aa, C0, C1, C2)                          \
  do {                                                   \
    Aa = *(const float4*)(p1);                           \
    C0 = ok0 ? *(const float4*)(p2) : z4;                \
    C1 = ok1 ? *(const float4*)(p2 + 4) : z4;            \
    C2 = ok2 ? *(const float4*)(p2 + 8) : z4;            \
    p1 += HW;                                            \
    p2 += HW;                                            \
  } while (0)

#define FMASET(Aa, C0, C1, C2)                                          \
  do {                                                                  \
    const float av[4] = {Aa.x, Aa.y, Aa.z, Aa.w};                       \
    const float rv[12] = {C0.x, C0.y, C0.z, C0.w, C1.x, C1.y, C1.z,     \
                          C1.w, C2.x, C2.y, C2.z, C2.w};                \
    _Pragma("unroll") for (int dx = 0; dx < 9; ++dx) {                  \
      acc[dx][0] += av[0] * rv[dx + 0];                                 \
      acc[dx][1] += av[1] * rv[dx + 1];                                 \
      acc[dx][2] += av[2] * rv[dx + 2];                                 \
      acc[dx][3] += av[3] * rv[dx + 3];                                 \
    }                                                                   \
  } while (0)

  // prologue: channels 0,1 into A,B
  LOADSET(aA, c0A, c1A, c2A);
  LOADSET(aB, c0B, c1B, c2B);

  // steady state: 42 iterations x 3 channels; loads run 2 bodies ahead.
#pragma unroll 1
  for (int i = 0; i < 42; ++i) {
    LOADSET(aC, c0C, c1C, c2C);   // c = 3i+2
    FMASET(aA, c0A, c1A, c2A);    // c = 3i
    LOADSET(aA, c0A, c1A, c2A);   // c = 3i+3
    FMASET(aB, c0B, c1B, c2B);    // c = 3i+1
    LOADSET(aB, c0B, c1B, c2B);   // c = 3i+4
    FMASET(aC, c0C, c1C, c2C);    // c = 3i+2
  }
  // tail: channels 126,127 (in A,B)
  FMASET(aA, c0A, c1A, c2A);
  FMASET(aB, c0B, c1B, c2B);

#undef LOADSET
#undef FMASET

  // epilogue: out[b][dy*9+dx][y][xb..xb+3]
  const float invc = 1.0f / 128.0f;
#pragma unroll
  for (int dx = 0; dx < 9; ++dx) {
    float4 o;
    o.x = acc[dx][0] * invc;
    o.y = acc[dx][1] * invc;
    o.z = acc[dx][2] * invc;
    o.w = acc[dx][3] * invc;
    const size_t oidx =
        (((size_t)b * 81 + (dy * 9 + dx)) * Hh + y) * Ww + xb;
    *(float4*)&outg[oidx] = o;
  }
}

extern "C" void kernel_launch(void* const* d_in, const int* in_sizes, int n_in,
                              void* d_out, int out_size, void* d_ws, size_t ws_size,
                              hipStream_t stream) {
  const float* x1 = (const float*)d_in[0];
  const float* x2 = (const float*)d_in[1];
  float* out = (float*)d_out;
  corr_kernel<<<dim3(1152), dim3(NT), 0, stream>>>(x1, x2, out);
}

// Round 6
// 936.948 us; speedup vs baseline: 2.6178x; 2.6178x over previous
//
#include <hip/hip_runtime.h>

// Correlation (FlowNet-style), kernel=1, stride=1, md=pad=4.
// B=8, C=128, H=W=192 -> out [8, 81, 192, 192] fp32.
//
// Round-6: no LDS; flat wave->(tile,dy) mapping; triple-buffered register
// pipeline with sched_barrier-pinned distance-2 prefetch.
//  - work item g in [0,10368): tile = g/9, dy = g%9. tile = (b, xt, yt),
//    tile size 8y x 32x. 256-thr blocks = 4 waves; grid 2592 = 8 XCDs x 324.
//    XCD k processes exactly batch k (1296 items = 144 tiles); the 9 dy
//    consumers of each x2 row are consecutive waves on one XCD -> L2 hits.
//  - thread: 4 x-px; per channel 1 x1 float4 + 3 x2 float4 -> 36 FMA;
//    acc[9][4] = 36 VGPR, 3 load buffers x 16 = 48 VGPR.
//  - pipeline: LOAD(c+2) / sched_barrier / FMA(c) rotation -> the compiler
//    cannot sink loads to their uses (R2's silent failure); load-to-use
//    distance = 2 FMA bodies (~720 wall cyc at 5 waves/SIMD).

#define NT 256

__global__ __launch_bounds__(NT)
void corr_kernel(const float* __restrict__ x1g, const float* __restrict__ x2g,
                 float* __restrict__ outg) {
  constexpr int Cc = 128, Hh = 192, Ww = 192, HW = Hh * Ww;

  // XCD-chunked swizzle over blocks: 2592 = 8 x 324.
  const int bid  = blockIdx.x;
  const int xbid = (bid & 7) * 324 + (bid >> 3);
  const int w    = (int)threadIdx.x >> 6;
  const int g    = xbid * 4 + w;        // 0..10367
  const int tile = g / 9;               // 0..1151
  const int dy   = g - 9 * tile;        // 0..8
  const int yt = tile % 24;
  const int t2 = tile / 24;
  const int xt = t2 % 6;
  const int b  = t2 / 6;
  const int y0 = yt * 8, x0 = xt * 32;

  const int lane = (int)threadIdx.x & 63;
  const int tx   = lane & 7;    // 4 px each -> 32 cols
  const int ty   = lane >> 3;   // 8 rows

  const int y  = y0 + ty;
  const int xb = x0 + 4 * tx;
  const int row = y + dy - 4;
  const bool rowok = (row >= 0) && (row < Hh);
  const int rowc = rowok ? row : 0;

  // x2 window cols xb-4..xb+7; 16B slots fully in- or out-of-range.
  const bool ok0 = rowok && (xb >= 4);
  const bool ok1 = rowok;
  const bool ok2 = rowok && (xb <= 184);

  const float* p1 = x1g + ((size_t)(b * Cc) * Hh + y) * Ww + xb;
  const float* p2 = x2g + ((size_t)(b * Cc) * Hh + rowc) * Ww + (xb - 4);

  float acc[9][4];
#pragma unroll
  for (int d = 0; d < 9; ++d)
#pragma unroll
    for (int q = 0; q < 4; ++q) acc[d][q] = 0.f;

  const float4 z4 = make_float4(0.f, 0.f, 0.f, 0.f);
  float4 aA, c0A, c1A, c2A;
  float4 aB, c0B, c1B, c2B;
  float4 aC, c0C, c1C, c2C;

#define LOADSET(Aa, C0, C1, C2)                          \
  do {                                                   \
    Aa = *(const float4*)(p1);                           \
    C0 = ok0 ? *(const float4*)(p2) : z4;                \
    C1 = ok1 ? *(const float4*)(p2 + 4) : z4;            \
    C2 = ok2 ? *(const float4*)(p2 + 8) : z4;            \
    p1 += HW;                                            \
    p2 += HW;                                            \
    __builtin_amdgcn_sched_barrier(0);                   \
  } while (0)

#define FMASET(Aa, C0, C1, C2)                                          \
  do {                                                                  \
    const float av[4] = {Aa.x, Aa.y, Aa.z, Aa.w};                       \
    const float rv[12] = {C0.x, C0.y, C0.z, C0.w, C1.x, C1.y, C1.z,     \
                          C1.w, C2.x, C2.y, C2.z, C2.w};                \
    _Pragma("unroll") for (int dx = 0; dx < 9; ++dx) {                  \
      acc[dx][0] += av[0] * rv[dx + 0];                                 \
      acc[dx][1] += av[1] * rv[dx + 1];                                 \
      acc[dx][2] += av[2] * rv[dx + 2];                                 \
      acc[dx][3] += av[3] * rv[dx + 3];                                 \
    }                                                                   \
  } while (0)

  // prologue: channels 0,1 into A,B
  LOADSET(aA, c0A, c1A, c2A);
  LOADSET(aB, c0B, c1B, c2B);

  // steady state: 42 iterations x 3 channels; loads fly 2 bodies ahead.
#pragma unroll 1
  for (int i = 0; i < 42; ++i) {
    LOADSET(aC, c0C, c1C, c2C);   // load c = 3i+2
    FMASET(aA, c0A, c1A, c2A);    // fma  c = 3i
    LOADSET(aA, c0A, c1A, c2A);   // load c = 3i+3
    FMASET(aB, c0B, c1B, c2B);    // fma  c = 3i+1
    LOADSET(aB, c0B, c1B, c2B);   // load c = 3i+4
    FMASET(aC, c0C, c1C, c2C);    // fma  c = 3i+2
  }
  // tail: channels 126,127 (sitting in A,B)
  FMASET(aA, c0A, c1A, c2A);
  FMASET(aB, c0B, c1B, c2B);

#undef LOADSET
#undef FMASET

  // epilogue: out[b][dy*9+dx][y][xb..xb+3]
  const float invc = 1.0f / 128.0f;
#pragma unroll
  for (int dx = 0; dx < 9; ++dx) {
    float4 o;
    o.x = acc[dx][0] * invc;
    o.y = acc[dx][1] * invc;
    o.z = acc[dx][2] * invc;
    o.w = acc[dx][3] * invc;
    const size_t oidx =
        (((size_t)b * 81 + (dy * 9 + dx)) * Hh + y) * Ww + xb;
    *(float4*)&outg[oidx] = o;
  }
}

extern "C" void kernel_launch(void* const* d_in, const int* in_sizes, int n_in,
                              void* d_out, int out_size, void* d_ws, size_t ws_size,
                              hipStream_t stream) {
  const float* x1 = (const float*)d_in[0];
  const float* x2 = (const float*)d_in[1];
  float* out = (float*)d_out;
  // grid: 10368 wave-items / 4 waves per block = 2592 blocks (8 x 324)
  corr_kernel<<<dim3(2592), dim3(NT), 0, stream>>>(x1, x2, out);
}

// Round 7
// 347.508 us; speedup vs baseline: 7.0581x; 2.6962x over previous
//
#include <hip/hip_runtime.h>

// Correlation (FlowNet-style), kernel=1, stride=1, md=pad=4.
// B=8, C=128, H=W=192 -> out [8, 81, 192, 192] fp32.
//
// Round-7: LDS staging, conflict-free stride, 8 px/thread.
//  - 576 tiles (8b x 3xt x 24yt), tile 8y x 64x; 3 dy-groups per tile ->
//    1728 blocks of 192 thr (3 waves; wave w -> dy = 3g + w).
//  - x2 staged in LDS: 10 rows (y0+3g-4 .. +5) x 72 cols (x0-4 .. x0+67),
//    ROW STRIDE 76 floats -> b128 reads at (w+ty)*76 + 8tx + 4k have
//    bank-quad starts {12r+8tx+4k} mod 32: 8 distinct quads x 2 lanes
//    = uniform 2-way = conflict-free (R1/R4 died on stride%32==0 -> 8-way).
//  - x1 read from GLOBAL (shared by 9 dy-waves via L1/L2, no LDS cost).
//  - double-buffered chunks of CB=2 channels; stage loads issued one full
//    compute phase ahead; one barrier per chunk.
//  - thread: 8 x-px; per channel 4 LDS b128 + 2 global float4 -> 72 FMA;
//    acc[9][8] = 72 VGPR.

#define NT 192

__global__ __launch_bounds__(NT)
void corr_kernel(const float* __restrict__ x1g, const float* __restrict__ x2g,
                 float* __restrict__ outg) {
  constexpr int Cc = 128, Hh = 192, Ww = 192, HW = Hh * Ww;
  constexpr int CB = 2;                  // channels per chunk
  constexpr int NCK = Cc / CB;           // 64 chunks
  constexpr int XS = 76;                 // x2 LDS row stride (floats)
  constexpr int ROWS = 10;               // x2 rows per dy-triple
  constexpr int CHF = ROWS * XS;         // 760 floats per channel
  constexpr int BUF = CB * CHF;          // 1520 floats per buffer
  constexpr int NSLOT = CB * ROWS * 18;  // 360 float4 staging slots

  __shared__ __align__(16) float lds[2 * BUF];  // 12.2 KB

  // XCD-chunked swizzle: 1728 = 8 XCDs x 216; g fastest, then yt.
  // XCD k gets tiles 72k..72k+71 == exactly batch k.
  const int bid = blockIdx.x;
  const int wid = (bid & 7) * 216 + (bid >> 3);
  const int tile = wid / 3;
  const int g    = wid - 3 * tile;
  const int yt = tile % 24;
  const int t2 = tile / 24;
  const int xt = t2 % 3;
  const int b  = t2 / 3;
  const int y0 = yt * 8, x0 = xt * 64;

  const int tid  = (int)threadIdx.x;
  const int w    = tid >> 6;    // 0..2
  const int lane = tid & 63;
  const int tx   = lane & 7;    // 8 px each -> 64 cols
  const int ty   = lane >> 3;   // 8 rows
  const int dy   = 3 * g + w;

  const int y  = y0 + ty;
  const int xb = x0 + 8 * tx;

  // ---- staging descriptors (2 float4 slots per thread) ----
  const float* x2b = x2g + (size_t)(b * Cc) * HW;
  int  goff[2], loff[2];
  bool hasS[2], okS[2];
#pragma unroll
  for (int s = 0; s < 2; ++s) {
    const int idx = tid + s * NT;
    hasS[s] = (idx < NSLOT);
    const int cc = idx / 180;            // channel within chunk
    const int rem = idx - cc * 180;
    const int i = rem / 18;              // row 0..9
    const int f = rem - 18 * i;          // float4 col 0..17
    const int grow = y0 + 3 * g - 4 + i;
    const int gcol = x0 - 4 + 4 * f;
    okS[s] = hasS[s] && grow >= 0 && grow < Hh && gcol >= 0 && gcol <= Ww - 4;
    const int rc = grow < 0 ? 0 : (grow >= Hh ? Hh - 1 : grow);
    const int cl = gcol < 0 ? 0 : (gcol > Ww - 4 ? Ww - 4 : gcol);
    goff[s] = (cc * Hh + rc) * Ww + cl;
    loff[s] = cc * CHF + i * XS + 4 * f;
  }

  const float4 z4 = make_float4(0.f, 0.f, 0.f, 0.f);
  float4 sreg[2];
  int gbase = 0;

  auto ldstage = [&]() {
#pragma unroll
    for (int s = 0; s < 2; ++s)
      sreg[s] = okS[s] ? *(const float4*)(x2b + gbase + goff[s]) : z4;
    gbase += CB * HW;
  };
  auto dswr = [&](int base) {
#pragma unroll
    for (int s = 0; s < 2; ++s)
      if (hasS[s]) *(float4*)&lds[base + loff[s]] = sreg[s];
  };

  const float* p1 = x1g + ((size_t)(b * Cc) * Hh + y) * Ww + xb;

  float acc[9][8];
#pragma unroll
  for (int d = 0; d < 9; ++d)
#pragma unroll
    for (int q = 0; q < 8; ++q) acc[d][q] = 0.f;

  // prologue: chunk0 -> buf0; issue chunk1 loads
  ldstage();
  dswr(0);
  ldstage();

  const int ro = (w + ty) * XS + 8 * tx;  // window base within channel block

#pragma unroll 1
  for (int k = 0; k < NCK; ++k) {
    __syncthreads();  // buf[k&1] (chunk k) visible; prior readers done
    if (k + 1 < NCK) dswr(((k + 1) & 1) * BUF);  // write chunk k+1
    if (k + 2 < NCK) ldstage();                  // issue chunk k+2 loads
    const int base = (k & 1) * BUF;

#pragma unroll
    for (int cc = 0; cc < CB; ++cc) {
      const float4 a0 = *(const float4*)(p1);
      const float4 a1 = *(const float4*)(p1 + 4);
      p1 += HW;
      const float* rr = &lds[base + cc * CHF + ro];
      const float4 b0 = *(const float4*)(rr);
      const float4 b1 = *(const float4*)(rr + 4);
      const float4 b2 = *(const float4*)(rr + 8);
      const float4 b3 = *(const float4*)(rr + 12);
      const float av[8] = {a0.x, a0.y, a0.z, a0.w, a1.x, a1.y, a1.z, a1.w};
      const float rv[16] = {b0.x, b0.y, b0.z, b0.w, b1.x, b1.y, b1.z, b1.w,
                            b2.x, b2.y, b2.z, b2.w, b3.x, b3.y, b3.z, b3.w};
#pragma unroll
      for (int dx = 0; dx < 9; ++dx)
#pragma unroll
        for (int q = 0; q < 8; ++q)
          acc[dx][q] += av[q] * rv[dx + q];
    }
  }

  // epilogue: out[b][dy*9+dx][y][xb..xb+7]
  const float invc = 1.0f / 128.0f;
#pragma unroll
  for (int dx = 0; dx < 9; ++dx) {
    float4 o0, o1;
    o0.x = acc[dx][0] * invc; o0.y = acc[dx][1] * invc;
    o0.z = acc[dx][2] * invc; o0.w = acc[dx][3] * invc;
    o1.x = acc[dx][4] * invc; o1.y = acc[dx][5] * invc;
    o1.z = acc[dx][6] * invc; o1.w = acc[dx][7] * invc;
    const size_t oidx =
        (((size_t)b * 81 + (dy * 9 + dx)) * Hh + y) * Ww + xb;
    *(float4*)&outg[oidx] = o0;
    *(float4*)&outg[oidx + 4] = o1;
  }
}

extern "C" void kernel_launch(void* const* d_in, const int* in_sizes, int n_in,
                              void* d_out, int out_size, void* d_ws, size_t ws_size,
                              hipStream_t stream) {
  const float* x1 = (const float*)d_in[0];
  const float* x2 = (const float*)d_in[1];
  float* out = (float*)d_out;
  // grid: 576 tiles x 3 dy-groups = 1728 blocks (divisible by 8 XCDs)
  corr_kernel<<<dim3(1728), dim3(NT), 0, stream>>>(x1, x2, out);
}

// Round 8
// 169.748 us; speedup vs baseline: 14.4493x; 2.0472x over previous
//
#include <hip/hip_runtime.h>

// Correlation (FlowNet-style), kernel=1, stride=1, md=pad=4.
// B=8, C=128, H=W=192 -> out [8, 81, 192, 192] fp32.
//
// Round-8: R7 structure (LDS x2 staging, stride-76 conflict-avoidance,
// 8 px/thread) with the spill fixed.
//  - __launch_bounds__(192, 2): VGPR cap 256 (permissive) -> compiler can
//    hold acc[9][8]=72 + staging 8 + x1 16 + window 16 + addr without
//    scratch. R7's VGPR=80 allocation spilled (~235 MB extra HBM writes).
//  - x1 loads for the whole chunk hoisted to chunk top -> L2 latency hides
//    under the first channel's LDS reads.
//  - 576 tiles (8b x 3xt x 24yt), tile 8y x 64x; 3 dy-groups/tile ->
//    1728 blocks of 192 thr (3 waves; wave w -> dy = 3g + w).
//  - x2 LDS: 10 rows x stride 76 floats, double-buffered CB=2 channels,
//    one barrier per chunk, stage loads issued 2 chunks ahead.

#define NT 192

__global__ __launch_bounds__(NT, 2)
void corr_kernel(const float* __restrict__ x1g, const float* __restrict__ x2g,
                 float* __restrict__ outg) {
  constexpr int Cc = 128, Hh = 192, Ww = 192, HW = Hh * Ww;
  constexpr int CB = 2;                  // channels per chunk
  constexpr int NCK = Cc / CB;           // 64 chunks
  constexpr int XS = 76;                 // x2 LDS row stride (floats)
  constexpr int ROWS = 10;               // x2 rows per dy-triple
  constexpr int CHF = ROWS * XS;         // 760 floats per channel
  constexpr int BUF = CB * CHF;          // 1520 floats per buffer
  constexpr int NSLOT = CB * ROWS * 18;  // 360 float4 staging slots

  __shared__ __align__(16) float lds[2 * BUF];  // 12.2 KB

  // XCD-chunked swizzle: 1728 = 8 XCDs x 216; XCD k == batch k exactly.
  const int bid = blockIdx.x;
  const int wid = (bid & 7) * 216 + (bid >> 3);
  const int tile = wid / 3;
  const int g    = wid - 3 * tile;
  const int yt = tile % 24;
  const int t2 = tile / 24;
  const int xt = t2 % 3;
  const int b  = t2 / 3;
  const int y0 = yt * 8, x0 = xt * 64;

  const int tid  = (int)threadIdx.x;
  const int w    = tid >> 6;    // 0..2
  const int lane = tid & 63;
  const int tx   = lane & 7;    // 8 px each -> 64 cols
  const int ty   = lane >> 3;   // 8 rows
  const int dy   = 3 * g + w;

  const int y  = y0 + ty;
  const int xb = x0 + 8 * tx;

  // ---- staging descriptors (2 float4 slots per thread) ----
  const float* x2b = x2g + (size_t)(b * Cc) * HW;
  int  goff[2], loff[2];
  bool hasS[2], okS[2];
#pragma unroll
  for (int s = 0; s < 2; ++s) {
    const int idx = tid + s * NT;
    hasS[s] = (idx < NSLOT);
    const int cc = idx / 180;            // channel within chunk
    const int rem = idx - cc * 180;
    const int i = rem / 18;              // row 0..9
    const int f = rem - 18 * i;          // float4 col 0..17
    const int grow = y0 + 3 * g - 4 + i;
    const int gcol = x0 - 4 + 4 * f;
    okS[s] = hasS[s] && grow >= 0 && grow < Hh && gcol >= 0 && gcol <= Ww - 4;
    const int rc = grow < 0 ? 0 : (grow >= Hh ? Hh - 1 : grow);
    const int cl = gcol < 0 ? 0 : (gcol > Ww - 4 ? Ww - 4 : gcol);
    goff[s] = (cc * Hh + rc) * Ww + cl;
    loff[s] = cc * CHF + i * XS + 4 * f;
  }

  const float4 z4 = make_float4(0.f, 0.f, 0.f, 0.f);
  float4 sreg0, sreg1;
  int gbase = 0;

  auto ldstage = [&]() {
    sreg0 = okS[0] ? *(const float4*)(x2b + gbase + goff[0]) : z4;
    sreg1 = okS[1] ? *(const float4*)(x2b + gbase + goff[1]) : z4;
    gbase += CB * HW;
  };
  auto dswr = [&](int base) {
    if (hasS[0]) *(float4*)&lds[base + loff[0]] = sreg0;
    if (hasS[1]) *(float4*)&lds[base + loff[1]] = sreg1;
  };

  const float* p1 = x1g + ((size_t)(b * Cc) * Hh + y) * Ww + xb;

  float acc[9][8];
#pragma unroll
  for (int d = 0; d < 9; ++d)
#pragma unroll
    for (int q = 0; q < 8; ++q) acc[d][q] = 0.f;

  // prologue: chunk0 -> buf0; issue chunk1 loads
  ldstage();
  dswr(0);
  ldstage();

  const int ro = (w + ty) * XS + 8 * tx;  // window base within channel block

#pragma unroll 1
  for (int k = 0; k < NCK; ++k) {
    __syncthreads();  // buf[k&1] (chunk k) visible; prior readers done
    if (k + 1 < NCK) dswr(((k + 1) & 1) * BUF);  // write chunk k+1
    if (k + 2 < NCK) ldstage();                  // issue chunk k+2 loads
    const int base = (k & 1) * BUF;

    // hoist this chunk's x1 loads: latency hides under ch0's LDS reads
    const float4 a00 = *(const float4*)(p1);
    const float4 a01 = *(const float4*)(p1 + 4);
    const float4 a10 = *(const float4*)(p1 + HW);
    const float4 a11 = *(const float4*)(p1 + HW + 4);
    p1 += 2 * HW;

#pragma unroll
    for (int cc = 0; cc < CB; ++cc) {
      const float* rr = &lds[base + cc * CHF + ro];
      const float4 b0 = *(const float4*)(rr);
      const float4 b1 = *(const float4*)(rr + 4);
      const float4 b2 = *(const float4*)(rr + 8);
      const float4 b3 = *(const float4*)(rr + 12);
      const float4 a0 = cc ? a10 : a00;
      const float4 a1 = cc ? a11 : a01;
      const float av[8] = {a0.x, a0.y, a0.z, a0.w, a1.x, a1.y, a1.z, a1.w};
      const float rv[16] = {b0.x, b0.y, b0.z, b0.w, b1.x, b1.y, b1.z, b1.w,
                            b2.x, b2.y, b2.z, b2.w, b3.x, b3.y, b3.z, b3.w};
#pragma unroll
      for (int dx = 0; dx < 9; ++dx)
#pragma unroll
        for (int q = 0; q < 8; ++q)
          acc[dx][q] += av[q] * rv[dx + q];
    }
  }

  // epilogue: out[b][dy*9+dx][y][xb..xb+7]
  const float invc = 1.0f / 128.0f;
#pragma unroll
  for (int dx = 0; dx < 9; ++dx) {
    float4 o0, o1;
    o0.x = acc[dx][0] * invc; o0.y = acc[dx][1] * invc;
    o0.z = acc[dx][2] * invc; o0.w = acc[dx][3] * invc;
    o1.x = acc[dx][4] * invc; o1.y = acc[dx][5] * invc;
    o1.z = acc[dx][6] * invc; o1.w = acc[dx][7] * invc;
    const size_t oidx =
        (((size_t)b * 81 + (dy * 9 + dx)) * Hh + y) * Ww + xb;
    *(float4*)&outg[oidx] = o0;
    *(float4*)&outg[oidx + 4] = o1;
  }
}

extern "C" void kernel_launch(void* const* d_in, const int* in_sizes, int n_in,
                              void* d_out, int out_size, void* d_ws, size_t ws_size,
                              hipStream_t stream) {
  const float* x1 = (const float*)d_in[0];
  const float* x2 = (const float*)d_in[1];
  float* out = (float*)d_out;
  // grid: 576 tiles x 3 dy-groups = 1728 blocks (divisible by 8 XCDs)
  corr_kernel<<<dim3(1728), dim3(NT), 0, stream>>>(x1, x2, out);
}